// Round 6
// baseline (193.442 us; speedup 1.0000x reference)
//
#include <hip/hip_runtime.h>

#define NPTS 8192
#define DIM 64
#define EPSF 1e-7f
#define LN2F 0.69314718055994531f

typedef unsigned short u16;
typedef __attribute__((ext_vector_type(8))) short bf16x8;   // 8 bf16 (4 VGPRs)
typedef __attribute__((ext_vector_type(8))) unsigned short u16x8;
typedef __attribute__((ext_vector_type(4))) float f32x4;

// ---- kernel 1: split x into bf16 hi/lo; store hsq=-sq/2, rcpom=1/(1-sq), m4r=-4/(1-sq)
__global__ void prep_kernel(const float* __restrict__ x,
                            u16* __restrict__ hi, u16* __restrict__ lo,
                            float* __restrict__ hsq, float* __restrict__ rcpom,
                            float* __restrict__ m4r) {
    int g = blockIdx.x * blockDim.x + threadIdx.x;   // 0 .. NPTS*8-1
    int row = g >> 3, sub = g & 7;
    const float* xp = x + row * DIM + sub * 8;
    float v[8];
    float s = 0.f;
#pragma unroll
    for (int k = 0; k < 8; k++) { v[k] = xp[k]; s = fmaf(v[k], v[k], s); }
    s += __shfl_xor(s, 1);
    s += __shfl_xor(s, 2);
    s += __shfl_xor(s, 4);
    u16x8 h, l;
#pragma unroll
    for (int k = 0; k < 8; k++) {
        unsigned int bits = __float_as_uint(v[k]);
        u16 hb = (u16)(bits >> 16);                       // truncation: hi exact bf16
        float hf = __uint_as_float(((unsigned int)hb) << 16);
        float lf = v[k] - hf;                             // exact in fp32
        u16 lb = (u16)(__float_as_uint(lf) >> 16);
        h[k] = hb; l[k] = lb;
    }
    *(u16x8*)(hi + row * DIM + sub * 8) = h;
    *(u16x8*)(lo + row * DIM + sub * 8) = l;
    if (sub == 0) {
        float r = 1.0f / (1.0f - s);
        hsq[row] = -0.5f * s;
        rcpom[row] = r;
        m4r[row] = -4.0f * r;
    }
}

// ---- kernel 2: fused MFMA Gram tile + hyperbolic epilogue -------------------
// Block tile 64(i) x 256(j); 4 waves, wave tile 16(i) x 256(j).
// D = dot - sq_i/2 - sq_j/2 (C-init folds the norms); u = max(D*rcpi*m4r_j,EPS).
// exp(-d) = (1+u) - sqrt(u(2+u));  d/ln2 = log2((1+u) + sqrt(u(2+u))).
// Two 3-deep MFMA chains (acc0/acc1) instead of one 6-deep to cut dep latency;
// 16-row wave tile keeps regs ~<100 so 5 waves/SIMD fit (launch_bounds(256,5)).
__global__ void __launch_bounds__(256, 5) pair_mfma(
        const u16* __restrict__ hi, const u16* __restrict__ lo,
        const float* __restrict__ hsq, const float* __restrict__ rcpom,
        const float* __restrict__ m4r, const int* __restrict__ labels,
        float* __restrict__ Sarr, float* __restrict__ Tarr) {
    int tid = threadIdx.x;
    int wave = tid >> 6, lane = tid & 63;
    int quad = lane >> 4, l15 = lane & 15;
    int i0 = blockIdx.x * 64 + wave * 16;
    int j0 = blockIdx.y * 256;

    bf16x8 a_hi[2], a_lo[2];
#pragma unroll
    for (int ks = 0; ks < 2; ks++) {
        int off = (i0 + l15) * DIM + ks * 32 + quad * 8;
        a_hi[ks] = *(const bf16x8*)(hi + off);
        a_lo[ks] = *(const bf16x8*)(lo + off);
    }

    float hsqi[4], rcpi[4]; int labi[4];
#pragma unroll
    for (int r = 0; r < 4; r++) {
        int row = i0 + quad * 4 + r;
        hsqi[r] = hsq[row];
        rcpi[r] = rcpom[row];
        labi[r] = labels[row];
    }

    float Sx[4] = {0.f, 0.f, 0.f, 0.f};
    float Tx[4] = {0.f, 0.f, 0.f, 0.f};

#pragma unroll 2
    for (int t = 0; t < 16; t++) {
        int jg = j0 + t * 16 + l15;
        bf16x8 b_hi[2], b_lo[2];
#pragma unroll
        for (int ks = 0; ks < 2; ks++) {
            int off = jg * DIM + ks * 32 + quad * 8;
            b_hi[ks] = *(const bf16x8*)(hi + off);
            b_lo[ks] = *(const bf16x8*)(lo + off);
        }
        float hsqj = hsq[jg];
        float mj = m4r[jg];
        int labj = labels[jg];

        f32x4 acc0, acc1;
#pragma unroll
        for (int r = 0; r < 4; r++) { acc0[r] = hsqi[r] + hsqj; acc1[r] = 0.f; }
        acc0 = __builtin_amdgcn_mfma_f32_16x16x32_bf16(a_lo[0], b_hi[0], acc0, 0, 0, 0);
        acc1 = __builtin_amdgcn_mfma_f32_16x16x32_bf16(a_lo[1], b_hi[1], acc1, 0, 0, 0);
        acc0 = __builtin_amdgcn_mfma_f32_16x16x32_bf16(a_hi[0], b_lo[0], acc0, 0, 0, 0);
        acc1 = __builtin_amdgcn_mfma_f32_16x16x32_bf16(a_hi[1], b_lo[1], acc1, 0, 0, 0);
        acc0 = __builtin_amdgcn_mfma_f32_16x16x32_bf16(a_hi[0], b_hi[0], acc0, 0, 0, 0);
        acc1 = __builtin_amdgcn_mfma_f32_16x16x32_bf16(a_hi[1], b_hi[1], acc1, 0, 0, 0);

#pragma unroll
        for (int r = 0; r < 4; r++) {
            float dot = acc0[r] + acc1[r];                    // D = dot - (sqi+sqj)/2
            float u = fmaxf(dot * rcpi[r] * mj, EPSF);
            float srt = __builtin_amdgcn_sqrtf(fmaf(u, u, u + u));
            float opu = 1.0f + u;
            Sx[r] += opu - srt;                               // exp(-d)
            float l2 = __builtin_amdgcn_logf(opu + srt);      // d / ln2
            Tx[r] += (labj == labi[r]) ? l2 : 0.0f;
        }
    }

    // reduce over the 16 j-columns (lanes within a quad share rows)
#pragma unroll
    for (int r = 0; r < 4; r++) {
#pragma unroll
        for (int m = 1; m < 16; m <<= 1) {
            Sx[r] += __shfl_xor(Sx[r], m);
            Tx[r] += __shfl_xor(Tx[r], m);
        }
    }
    if (l15 == 0) {
#pragma unroll
        for (int r = 0; r < 4; r++) {
            int row = i0 + quad * 4 + r;
            atomicAdd(&Sarr[row], Sx[r]);
            atomicAdd(&Tarr[row], Tx[r]);
        }
    }
}

// ---- kernel 3: finalize, single block (histogram + loss + reduce) -----------
// loss_i = ln(S_i - st_self) + ln2*(T_i - l2_self)/(cnt[lab_i]-1)
__global__ void __launch_bounds__(1024) finalize_kernel(
        const float* __restrict__ S, const float* __restrict__ T,
        const int* __restrict__ labels, float* __restrict__ out) {
    __shared__ int chist[64][16];
    __shared__ float cntf[16];
    __shared__ float red[1024];
    int tid = threadIdx.x;
    chist[tid >> 4][tid & 15] = 0;
    __syncthreads();
    int rep = tid & 63;
    for (int i = tid; i < NPTS; i += 1024)
        atomicAdd(&chist[rep][labels[i]], 1);
    __syncthreads();
    if (tid < 16) {
        int s = 0;
#pragma unroll
        for (int k = 0; k < 64; k++) s += chist[k][tid];
        cntf[tid] = (float)(s - 1);
    }
    __syncthreads();

    float s0 = __builtin_amdgcn_sqrtf(EPSF * (2.0f + EPSF));
    float st0 = 1.0f + EPSF - s0;                        // self exp(-d) term
    float l20 = __builtin_amdgcn_logf(1.0f + EPSF + s0); // self log2 term
    float acc = 0.f;
    for (int i = tid; i < NPTS; i += 1024) {
        float p = cntf[labels[i]];
        acc += __logf(S[i] - st0) + (T[i] - l20) * LN2F / p;
    }
    red[tid] = acc;
    __syncthreads();
    for (int s = 512; s > 0; s >>= 1) {
        if (tid < s) red[tid] += red[tid + s];
        __syncthreads();
    }
    if (tid == 0) out[0] = red[0];
}

extern "C" void kernel_launch(void* const* d_in, const int* in_sizes, int n_in,
                              void* d_out, int out_size, void* d_ws, size_t ws_size,
                              hipStream_t stream) {
    const float* x = (const float*)d_in[0];
    const int* labels = (const int*)d_in[1];

    u16* hi = (u16*)d_ws;                 // NPTS*DIM u16
    u16* lo = hi + NPTS * DIM;            // NPTS*DIM u16
    float* hsq = (float*)(lo + NPTS * DIM);
    float* rcpom = hsq + NPTS;
    float* m4r = rcpom + NPTS;
    float* S = m4r + NPTS;
    float* T = S + NPTS;

    (void)hipMemsetAsync(S, 0, 2 * NPTS * sizeof(float), stream);

    prep_kernel<<<(NPTS * 8) / 256, 256, 0, stream>>>(x, hi, lo, hsq, rcpom, m4r);

    dim3 grid(NPTS / 64, NPTS / 256);
    pair_mfma<<<grid, 256, 0, stream>>>(hi, lo, hsq, rcpom, m4r, labels, S, T);

    finalize_kernel<<<1, 1024, 0, stream>>>(S, T, labels, (float*)d_out);
}